// Round 4
// baseline (117.787 us; speedup 1.0000x reference)
//
#include <hip/hip_runtime.h>

namespace {

constexpr int B = 4, L = 4096, HC = 4, D = 1024, K = 4, DIL = 2;
constexpr float EPS = 1e-5f;
constexpr int WROWS = 32;            // output rows per wave
constexpr int NT = L / WROWS;        // 128 strips along L
constexpr int BDIM = 256;            // 4 waves; wave w handles hc=w, same strip

__global__ __launch_bounds__(BDIM, 2) void engram_shortconv_wave(
    const float* __restrict__ x,
    const float* __restrict__ nw,
    const float* __restrict__ cw,
    float* __restrict__ out)
{
    const int tid  = threadIdx.x;
    const int hc   = tid >> 6;          // wave index = chunk index
    const int lane = tid & 63;

    const int blk = blockIdx.x;
    const int t   = blk & (NT - 1);     // 128 strips
    const int b   = blk >> 7;
    const int l0  = t * WROWS;

    const size_t rs = (size_t)HC * D;   // 4096 floats between rows
    // lane's base: floats p*256 + lane*4 within the hc chunk, p=0..3
    const float* xptr = x   + (size_t)b * L * rs + (size_t)hc * D + lane * 4;
    float*       optr = out + (size_t)b * L * rs + (size_t)hc * D + lane * 4;

    // ---- weights: fold norm gain into conv taps. lane owns 16 channels ----
    float wk[4][4][4];   // [p][j][k]
    #pragma unroll
    for (int p = 0; p < 4; ++p) {
        const float4 g = *(const float4*)(nw + (size_t)hc * D + p * 256 + lane * 4);
        const float gv[4] = { g.x, g.y, g.z, g.w };
        #pragma unroll
        for (int j = 0; j < 4; ++j) {
            const float4 w = *(const float4*)(cw + ((size_t)hc * D + p * 256 + lane * 4 + j) * K);
            wk[p][j][0] = w.x * gv[j]; wk[p][j][1] = w.y * gv[j];
            wk[p][j][2] = w.z * gv[j]; wk[p][j][3] = w.w * gv[j];
        }
    }

    float e0[16], e1[16], e2[16];   // scaled even-parity window (l-6,l-4,l-2)
    float o0[16], o1[16], o2[16];   // scaled odd-parity window
    float pf0[16], pf1[16];         // prefetch buffers (even / odd next rows)

    auto loadrow = [&](int l, float* dst) {
        if (l >= 0) {
            const int lc = (l < L) ? l : (L - 1);   // clamp prefetch overrun
            const float* rp = xptr + (size_t)lc * rs;
            #pragma unroll
            for (int p = 0; p < 4; ++p) {
                const float4 v = *(const float4*)(rp + p * 256);
                dst[p * 4 + 0] = v.x; dst[p * 4 + 1] = v.y;
                dst[p * 4 + 2] = v.z; dst[p * 4 + 3] = v.w;
            }
        } else {
            #pragma unroll
            for (int q = 0; q < 16; ++q) dst[q] = 0.0f;
        }
    };

    auto rms_scale = [&](float* v) {
        float ss = 0.0f;
        #pragma unroll
        for (int q = 0; q < 16; ++q) ss = fmaf(v[q], v[q], ss);
        #pragma unroll
        for (int off = 32; off >= 1; off >>= 1) ss += __shfl_xor(ss, off);
        const float inv = rsqrtf(ss * (1.0f / D) + EPS);
        #pragma unroll
        for (int q = 0; q < 16; ++q) v[q] *= inv;
    };

    // ---- prologue: 6 halo rows, scaled, into windows ----
    loadrow(l0 - 6, e0); rms_scale(e0);
    loadrow(l0 - 4, e1); rms_scale(e1);
    loadrow(l0 - 2, e2); rms_scale(e2);
    loadrow(l0 - 5, o0); rms_scale(o0);
    loadrow(l0 - 3, o1); rms_scale(o1);
    loadrow(l0 - 1, o2); rms_scale(o2);
    loadrow(l0,     pf0);
    loadrow(l0 + 1, pf1);

    // ---- main loop: 2 rows per iteration, windows static-indexed ----
    for (int i = 0; i < WROWS; i += 2) {
        // even row l = l0 + i
        rms_scale(pf0);
        {
            const float* rp = nullptr; (void)rp;
            float* orow = optr + (size_t)(l0 + i) * rs;
            #pragma unroll
            for (int p = 0; p < 4; ++p) {
                float4 o; float* op = &o.x;
                #pragma unroll
                for (int j = 0; j < 4; ++j) {
                    const int q = p * 4 + j;
                    float a = fmaf(wk[p][j][0], e0[q],
                              fmaf(wk[p][j][1], e1[q],
                              fmaf(wk[p][j][2], e2[q],
                                   wk[p][j][3] * pf0[q])));
                    op[j] = a / (1.0f + __expf(-a));
                }
                *(float4*)(orow + p * 256) = o;
            }
        }
        #pragma unroll
        for (int q = 0; q < 16; ++q) { e0[q] = e1[q]; e1[q] = e2[q]; e2[q] = pf0[q]; }
        loadrow(l0 + i + 2, pf0);

        // odd row l = l0 + i + 1
        rms_scale(pf1);
        {
            float* orow = optr + (size_t)(l0 + i + 1) * rs;
            #pragma unroll
            for (int p = 0; p < 4; ++p) {
                float4 o; float* op = &o.x;
                #pragma unroll
                for (int j = 0; j < 4; ++j) {
                    const int q = p * 4 + j;
                    float a = fmaf(wk[p][j][0], o0[q],
                              fmaf(wk[p][j][1], o1[q],
                              fmaf(wk[p][j][2], o2[q],
                                   wk[p][j][3] * pf1[q])));
                    op[j] = a / (1.0f + __expf(-a));
                }
                *(float4*)(orow + p * 256) = o;
            }
        }
        #pragma unroll
        for (int q = 0; q < 16; ++q) { o0[q] = o1[q]; o1[q] = o2[q]; o2[q] = pf1[q]; }
        loadrow(l0 + i + 3, pf1);
    }
}

} // namespace

extern "C" void kernel_launch(void* const* d_in, const int* in_sizes, int n_in,
                              void* d_out, int out_size, void* d_ws, size_t ws_size,
                              hipStream_t stream) {
    const float* x  = (const float*)d_in[0];   // [B, L, HC, D] f32
    const float* nw = (const float*)d_in[1];   // [HC, D] f32
    const float* cw = (const float*)d_in[2];   // [C, 1, K] f32
    float* out = (float*)d_out;                // [B, L, HC, D] f32

    const int nblocks = B * NT;                // 512 blocks x 4 waves = 2048 waves
    engram_shortconv_wave<<<dim3(nblocks), dim3(BDIM), 0, stream>>>(x, nw, cw, out);
}